// Round 16
// baseline (227.413 us; speedup 1.0000x reference)
//
#include <hip/hip_runtime.h>

// GNN surrogate — all-register MFMA chain (r15 structure), arrays replaced by
// EXPLICITLY NAMED registers (r15's half4 arrays were demoted to scratch:
// WRITE_SIZE 168 MB, VGPR only 84). Layout identity (verified r15): for
// mfma_f32_16x16x16_f16, C-frag [row=quad*4+r][col=lane&15] == operand
// [k=quad*4+j][m|n=lane&15]; pk4'd C-frag IS the next stage's operand
// (as B: contracts rows; as A: its transpose). Zero LDS, zero barriers.
// Folds (exact): M_l = W2[l]@W1[l+1], lift into W1eff (K=3 pad 16),
// v, u, cp as before.

typedef _Float16 f16;
typedef __attribute__((ext_vector_type(8))) _Float16 half8;
typedef __attribute__((ext_vector_type(4))) _Float16 half4;
typedef __attribute__((ext_vector_type(2))) __fp16 fp16x2;
typedef __attribute__((ext_vector_type(4))) float f32x4;

namespace {
constexpr int N = 128, H = 32;
constexpr int WS_ADJB = 0;       // f16 swizzled adj tiles [8g][4p][64lane][8] (32768 B)
constexpr int WS_W0B  = 32768;   // f16 [2t][64lane][4]  W1eff B-tiles        (1024 B)
constexpr int WS_MB   = 33792;   // f16 [2l][2t][2tp][64][4] Meff B-tiles     (4096 B)
constexpr int WS_BIAS = 37888;   // f32 [3][32]
constexpr int WS_V    = 38400;   // f32 [128]
constexpr int WS_U    = 38912;   // f32 [32]
constexpr int WS_C    = 39040;   // f32 [1]
}

static __device__ __forceinline__ half4 pk4(float a, float b, float c, float d) {
  union { half4 v; fp16x2 h[2]; } u;
  u.h[0] = __builtin_amdgcn_cvt_pkrtz(a, b);
  u.h[1] = __builtin_amdgcn_cvt_pkrtz(c, d);
  return u.v;
}
static __device__ __forceinline__ half4 relupk(f32x4 c) {
  const half4 z = {};
  return __builtin_elementwise_max(pk4(c[0], c[1], c[2], c[3]), z);
}
static __device__ __forceinline__ half4 pkc(f32x4 c) {
  return pk4(c[0], c[1], c[2], c[3]);
}

#define MF(A, B, C) __builtin_amdgcn_mfma_f32_16x16x16f16((A), (B), (C), 0, 0, 0)

// ---- prep: identical to r15 (verified) ----
__global__ void prep(const float* __restrict__ adj,
                     const float* __restrict__ W_lift,
                     const float* __restrict__ b_lift,
                     const float* __restrict__ W1,
                     const float* __restrict__ b1,
                     const float* __restrict__ W2,
                     const float* __restrict__ b2,
                     const float* __restrict__ W_ro,
                     const float* __restrict__ b_ro,
                     char* __restrict__ ws) {
  const int tid = threadIdx.x;
  f16* adjb  = (f16*)(ws + WS_ADJB);
  f16* w0b   = (f16*)(ws + WS_W0B);
  f16* mb    = (f16*)(ws + WS_MB);
  float* bia = (float*)(ws + WS_BIAS);
  float* v   = (float*)(ws + WS_V);
  float* u   = (float*)(ws + WS_U);
  float* cp  = (float*)(ws + WS_C);

  for (int e = tid; e < 2048; e += 256) {
    const int g = e >> 8, p = (e >> 6) & 3, lane = e & 63;
    const int lr = lane & 15, q = lane >> 4;
    const float* src = adj + (g * 16 + lr) * N;
    f16* dst = adjb + e * 8;
#pragma unroll
    for (int h = 0; h < 2; ++h)
#pragma unroll
      for (int jj = 0; jj < 4; ++jj)
        dst[h * 4 + jj] = (f16)src[(2 * p + h) * 16 + q * 4 + jj];
  }

  __shared__ float tmp[3][H][H];
  __shared__ float sred[N];
  for (int idx = tid; idx < 3 * H * H; idx += 256) {
    const int l = idx >> 10, rem = idx & 1023;
    const int k = rem >> 5, fo = rem & 31;
    float val = 0.f;
    if (l == 0) {
      if (k < 3) for (int c = 0; c < H; ++c) val += W_lift[k * H + c] * W1[c * H + fo];
    } else {
      const float* w2l = W2 + (l - 1) * H * H;
      const float* w1n = W1 + l * H * H;
      for (int c = 0; c < H; ++c) val += w2l[k * H + c] * w1n[c * H + fo];
    }
    tmp[l][k][fo] = val;
  }
  if (tid < N) {
    float s = 0.f;
    for (int i = 0; i < N; ++i) s += adj[i * N + tid];
    v[tid] = s * (1.0f / N);
    sred[tid] = s * (1.0f / N);
  }
  if (tid < H) {
    float s0 = b1[tid], s1 = b1[H + tid], s2 = b1[2 * H + tid];
    for (int c = 0; c < H; ++c) {
      s0 += b_lift[c] * W1[c * H + tid];
      s1 += b2[c] * W1[H * H + c * H + tid];
      s2 += b2[H + c] * W1[2 * H * H + c * H + tid];
    }
    bia[tid] = s0; bia[H + tid] = s1; bia[2 * H + tid] = s2;
    float su = 0.f;
    for (int c = 0; c < H; ++c) su += W2[2 * H * H + tid * H + c] * W_ro[c];
    u[tid] = su;
  }
  __syncthreads();
  for (int e = tid; e < 512; e += 256) {
    const int t = e >> 8, lane = (e >> 2) & 63, j = e & 3;
    const int lr = lane & 15, q = lane >> 4;
    w0b[e] = (f16)tmp[0][q * 4 + j][t * 16 + lr];
  }
  for (int e = tid; e < 2048; e += 256) {
    const int l = e >> 10, rem = e & 1023;
    const int t = rem >> 9, tp = (rem >> 8) & 1, lane = (rem >> 2) & 63, j = rem & 3;
    const int lr = lane & 15, q = lane >> 4;
    mb[e] = (f16)tmp[1 + l][t * 16 + q * 4 + j][tp * 16 + lr];
  }
  if (tid == 0) {
    float c2r = 0.f;
    for (int k = 0; k < H; ++k) c2r += b2[2 * H + k] * W_ro[k];
    float S = 0.f;
    for (int j = 0; j < N; ++j) S += sred[j];
    cp[0] = c2r * S + b_ro[0];
  }
}

__global__ __launch_bounds__(256, 3)
void gnn_mfma(const float* __restrict__ x,
              const char* __restrict__ ws,
              float* __restrict__ out) {
  const f16* adjb  = (const f16*)(ws + WS_ADJB);
  const f16* w0b   = (const f16*)(ws + WS_W0B);
  const f16* mb    = (const f16*)(ws + WS_MB);
  const float* bia = (const float*)(ws + WS_BIAS);
  const float* v   = (const float*)(ws + WS_V);
  const float* u   = (const float*)(ws + WS_U);
  const float* cp  = (const float*)(ws + WS_C);

  const int tid  = threadIdx.x;
  const int wave = tid >> 6;
  const int lane = tid & 63;
  const int lrow = lane & 15;
  const int quad = lane >> 4;
  const int b    = blockIdx.x * 4 + wave;

  const f32x4 zero = {0.f, 0.f, 0.f, 0.f};

  // explicitly named state registers (guaranteed promotion)
  half4 tf00, tf01, tf10, tf11, tf20, tf21, tf30, tf31,
        tf40, tf41, tf50, tf51, tf60, tf61, tf70, tf71;
  half4 pf00, pf01, pf02, pf03, pf04, pf05, pf06, pf07,
        pf10, pf11, pf12, pf13, pf14, pf15, pf16, pf17;

  // ---- L0: T0[node][fout] = relu(x·W1eff + b0) ----
  {
    const half4 w0 = *(const half4*)(w0b + (0 * 64 + lane) * 4);
    const half4 w1 = *(const half4*)(w0b + (1 * 64 + lane) * 4);
    const float bb0 = bia[lrow], bb1 = bia[16 + lrow];
    const f32x4 bi0 = {bb0, bb0, bb0, bb0};
    const f32x4 bi1 = {bb1, bb1, bb1, bb1};
#define L0G(g, TF0, TF1)                                                    \
    {                                                                        \
      half4 xa = {};                                                         \
      if (quad == 0) {                                                       \
        const float* xr = x + ((size_t)b * N + (g) * 16 + lrow) * 3;         \
        union { half4 v4; fp16x2 p[2]; } xu;                                 \
        xu.p[0] = __builtin_amdgcn_cvt_pkrtz(xr[0], xr[1]);                  \
        xu.p[1] = __builtin_amdgcn_cvt_pkrtz(xr[2], 0.f);                    \
        xa = xu.v4;                                                          \
      }                                                                      \
      TF0 = relupk(MF(xa, w0, bi0));                                         \
      TF1 = relupk(MF(xa, w1, bi1));                                         \
    }
    L0G(0, tf00, tf01) L0G(1, tf10, tf11) L0G(2, tf20, tf21) L0G(3, tf30, tf31)
    L0G(4, tf40, tf41) L0G(5, tf50, tf51) L0G(6, tf60, tf61) L0G(7, tf70, tf71)
#undef L0G
  }

  // G: P^T[fout t][node gi] = sum_p mfma(A=tf (transpose), B=adj tile pair)
#define GSTEP(gi, P0, P1)                                                    \
  {                                                                          \
    f32x4 a0 = zero, a1 = zero;                                              \
    union { half8 v8; half4 h[2]; } pu;                                      \
    pu.v8 = *(const half8*)(adjb + (((gi) * 4 + 0) * 64 + lane) * 8);        \
    a0 = MF(tf00, pu.h[0], a0); a1 = MF(tf01, pu.h[0], a1);                  \
    a0 = MF(tf10, pu.h[1], a0); a1 = MF(tf11, pu.h[1], a1);                  \
    pu.v8 = *(const half8*)(adjb + (((gi) * 4 + 1) * 64 + lane) * 8);        \
    a0 = MF(tf20, pu.h[0], a0); a1 = MF(tf21, pu.h[0], a1);                  \
    a0 = MF(tf30, pu.h[1], a0); a1 = MF(tf31, pu.h[1], a1);                  \
    pu.v8 = *(const half8*)(adjb + (((gi) * 4 + 2) * 64 + lane) * 8);        \
    a0 = MF(tf40, pu.h[0], a0); a1 = MF(tf41, pu.h[0], a1);                  \
    a0 = MF(tf50, pu.h[1], a0); a1 = MF(tf51, pu.h[1], a1);                  \
    pu.v8 = *(const half8*)(adjb + (((gi) * 4 + 3) * 64 + lane) * 8);        \
    a0 = MF(tf60, pu.h[0], a0); a1 = MF(tf61, pu.h[0], a1);                  \
    a0 = MF(tf70, pu.h[1], a0); a1 = MF(tf71, pu.h[1], a1);                  \
    P0 = pkc(a0); P1 = pkc(a1);                                              \
  }
#define GALL()                                                               \
  GSTEP(0, pf00, pf10) GSTEP(1, pf01, pf11) GSTEP(2, pf02, pf12)             \
  GSTEP(3, pf03, pf13) GSTEP(4, pf04, pf14) GSTEP(5, pf05, pf15)             \
  GSTEP(6, pf06, pf16) GSTEP(7, pf07, pf17)

  GALL()   // G0

  // L1: T1[node][fout'] = relu(P·Meff1 + c1)
  {
    const f16* mbl = mb + 0 * 1024;
    const half4 m00 = *(const half4*)(mbl + ((0 * 2 + 0) * 64 + lane) * 4);
    const half4 m01 = *(const half4*)(mbl + ((0 * 2 + 1) * 64 + lane) * 4);
    const half4 m10 = *(const half4*)(mbl + ((1 * 2 + 0) * 64 + lane) * 4);
    const half4 m11 = *(const half4*)(mbl + ((1 * 2 + 1) * 64 + lane) * 4);
    const float bb0 = bia[H + lrow], bb1 = bia[H + 16 + lrow];
    const f32x4 bi0 = {bb0, bb0, bb0, bb0};
    const f32x4 bi1 = {bb1, bb1, bb1, bb1};
#define L1G(P0, P1, TF0, TF1)                                                \
    {                                                                        \
      f32x4 c0 = MF(P0, m00, bi0); c0 = MF(P1, m10, c0);                     \
      f32x4 c1 = MF(P0, m01, bi1); c1 = MF(P1, m11, c1);                     \
      TF0 = relupk(c0); TF1 = relupk(c1);                                    \
    }
    L1G(pf00, pf10, tf00, tf01) L1G(pf01, pf11, tf10, tf11)
    L1G(pf02, pf12, tf20, tf21) L1G(pf03, pf13, tf30, tf31)
    L1G(pf04, pf14, tf40, tf41) L1G(pf05, pf15, tf50, tf51)
    L1G(pf06, pf16, tf60, tf61) L1G(pf07, pf17, tf70, tf71)
#undef L1G
  }

  GALL()   // G1
#undef GALL
#undef GSTEP

  // ---- L2 + folded readout ----
  {
    const f16* mbl = mb + 1 * 1024;
    const half4 m00 = *(const half4*)(mbl + ((0 * 2 + 0) * 64 + lane) * 4);
    const half4 m01 = *(const half4*)(mbl + ((0 * 2 + 1) * 64 + lane) * 4);
    const half4 m10 = *(const half4*)(mbl + ((1 * 2 + 0) * 64 + lane) * 4);
    const half4 m11 = *(const half4*)(mbl + ((1 * 2 + 1) * 64 + lane) * 4);
    const float bb0 = bia[2 * H + lrow], bb1 = bia[2 * H + 16 + lrow];
    const f32x4 bi0 = {bb0, bb0, bb0, bb0};
    const f32x4 bi1 = {bb1, bb1, bb1, bb1};
    const float u0 = u[lrow], u1 = u[16 + lrow];
    float partial = 0.f;
#define L2G(g, P0, P1)                                                       \
    {                                                                        \
      f32x4 c0 = MF(P0, m00, bi0); c0 = MF(P1, m10, c0);                     \
      f32x4 c1 = MF(P0, m01, bi1); c1 = MF(P1, m11, c1);                     \
      const float4 vv = *(const float4*)(v + (g) * 16 + quad * 4);           \
      partial += (fmaxf(c0[0], 0.f) * vv.x + fmaxf(c0[1], 0.f) * vv.y +      \
                  fmaxf(c0[2], 0.f) * vv.z + fmaxf(c0[3], 0.f) * vv.w) * u0 +\
                 (fmaxf(c1[0], 0.f) * vv.x + fmaxf(c1[1], 0.f) * vv.y +      \
                  fmaxf(c1[2], 0.f) * vv.z + fmaxf(c1[3], 0.f) * vv.w) * u1; \
    }
    L2G(0, pf00, pf10) L2G(1, pf01, pf11) L2G(2, pf02, pf12) L2G(3, pf03, pf13)
    L2G(4, pf04, pf14) L2G(5, pf05, pf15) L2G(6, pf06, pf16) L2G(7, pf07, pf17)
#undef L2G
#pragma unroll
    for (int off = 32; off > 0; off >>= 1) partial += __shfl_down(partial, off, 64);
    if (lane == 0) out[b] = partial + cp[0];
  }
}

extern "C" void kernel_launch(void* const* d_in, const int* in_sizes, int n_in,
                              void* d_out, int out_size, void* d_ws, size_t ws_size,
                              hipStream_t stream) {
  const float* x      = (const float*)d_in[0];
  const float* adj    = (const float*)d_in[1];
  const float* W_lift = (const float*)d_in[2];
  const float* b_lift = (const float*)d_in[3];
  const float* W1     = (const float*)d_in[4];
  const float* b1     = (const float*)d_in[5];
  const float* W2     = (const float*)d_in[6];
  const float* b2     = (const float*)d_in[7];
  const float* W_ro   = (const float*)d_in[8];
  const float* b_ro   = (const float*)d_in[9];
  char* ws = (char*)d_ws;
  float* o = (float*)d_out;

  const int B = in_sizes[0] / (N * 3);   // 16384
  hipLaunchKernelGGL(prep, dim3(1), dim3(256), 0, stream,
                     adj, W_lift, b_lift, W1, b1, W2, b2, W_ro, b_ro, ws);
  hipLaunchKernelGGL(gnn_mfma, dim3(B / 4), dim3(256), 0, stream,
                     x, (const char*)ws, o);
}

// Round 17
// 166.462 us; speedup vs baseline: 1.3662x; 1.3662x over previous
//
#include <hip/hip_runtime.h>

// GNN surrogate — all-register K=16 MFMA chain, spill-fixed (r17).
// r15/r16 diagnosis: __launch_bounds__(256,3) -> 168-reg unified budget,
// split 84 VGPR + 84 AGPR (VGPR_Count=84 both rounds) -> allocator spilled
// the state frags (WRITE 168-180 MB). Fix: __launch_bounds__(256,2) ->
// 256-reg budget; state (~32 half4) + accs + weights fit with headroom.
// Also purged all memory-typed union locals from the hot kernel.
// Layout identity (verified r15/r16 pass): for mfma_f32_16x16x16f16 the
// C-frag [row=quad*4+r][col=lane&15] == operand [k=quad*4+j][m|n=lane&15];
// a pk4'd C-frag IS the next stage's operand. Zero LDS, zero barriers.
// Folds (exact): M_l = W2[l]@W1[l+1], lift into W1eff (K=3 pad 16), v, u, cp.

typedef _Float16 f16;
typedef __attribute__((ext_vector_type(8))) _Float16 half8;
typedef __attribute__((ext_vector_type(4))) _Float16 half4;
typedef __attribute__((ext_vector_type(2))) __fp16 fp16x2;
typedef __attribute__((ext_vector_type(4))) float f32x4;

namespace {
constexpr int N = 128, H = 32;
constexpr int WS_ADJB = 0;       // f16 swizzled adj tiles [8g][4p][64lane][8] (32768 B)
constexpr int WS_W0B  = 32768;   // f16 [2t][64lane][4]  W1eff B-tiles        (1024 B)
constexpr int WS_MB   = 33792;   // f16 [2l][2t][2tp][64][4] Meff B-tiles     (4096 B)
constexpr int WS_BIAS = 37888;   // f32 [3][32]
constexpr int WS_V    = 38400;   // f32 [128]
constexpr int WS_U    = 38912;   // f32 [32]
constexpr int WS_C    = 39040;   // f32 [1]
}

static __device__ __forceinline__ half4 pk4(float a, float b, float c, float d) {
  union { half4 v; fp16x2 h[2]; } u;
  u.h[0] = __builtin_amdgcn_cvt_pkrtz(a, b);
  u.h[1] = __builtin_amdgcn_cvt_pkrtz(c, d);
  return u.v;
}
static __device__ __forceinline__ half4 relupk(f32x4 c) {
  const half4 z = {};
  return __builtin_elementwise_max(pk4(c[0], c[1], c[2], c[3]), z);
}
static __device__ __forceinline__ half4 pkc(f32x4 c) {
  return pk4(c[0], c[1], c[2], c[3]);
}

#define MF(A, B, C) __builtin_amdgcn_mfma_f32_16x16x16f16((A), (B), (C), 0, 0, 0)

// ---- prep: identical to r15/r16 (verified) ----
__global__ void prep(const float* __restrict__ adj,
                     const float* __restrict__ W_lift,
                     const float* __restrict__ b_lift,
                     const float* __restrict__ W1,
                     const float* __restrict__ b1,
                     const float* __restrict__ W2,
                     const float* __restrict__ b2,
                     const float* __restrict__ W_ro,
                     const float* __restrict__ b_ro,
                     char* __restrict__ ws) {
  const int tid = threadIdx.x;
  f16* adjb  = (f16*)(ws + WS_ADJB);
  f16* w0b   = (f16*)(ws + WS_W0B);
  f16* mb    = (f16*)(ws + WS_MB);
  float* bia = (float*)(ws + WS_BIAS);
  float* v   = (float*)(ws + WS_V);
  float* u   = (float*)(ws + WS_U);
  float* cp  = (float*)(ws + WS_C);

  for (int e = tid; e < 2048; e += 256) {
    const int g = e >> 8, p = (e >> 6) & 3, lane = e & 63;
    const int lr = lane & 15, q = lane >> 4;
    const float* src = adj + (g * 16 + lr) * N;
    f16* dst = adjb + e * 8;
#pragma unroll
    for (int h = 0; h < 2; ++h)
#pragma unroll
      for (int jj = 0; jj < 4; ++jj)
        dst[h * 4 + jj] = (f16)src[(2 * p + h) * 16 + q * 4 + jj];
  }

  __shared__ float tmp[3][H][H];
  __shared__ float sred[N];
  for (int idx = tid; idx < 3 * H * H; idx += 256) {
    const int l = idx >> 10, rem = idx & 1023;
    const int k = rem >> 5, fo = rem & 31;
    float val = 0.f;
    if (l == 0) {
      if (k < 3) for (int c = 0; c < H; ++c) val += W_lift[k * H + c] * W1[c * H + fo];
    } else {
      const float* w2l = W2 + (l - 1) * H * H;
      const float* w1n = W1 + l * H * H;
      for (int c = 0; c < H; ++c) val += w2l[k * H + c] * w1n[c * H + fo];
    }
    tmp[l][k][fo] = val;
  }
  if (tid < N) {
    float s = 0.f;
    for (int i = 0; i < N; ++i) s += adj[i * N + tid];
    v[tid] = s * (1.0f / N);
    sred[tid] = s * (1.0f / N);
  }
  if (tid < H) {
    float s0 = b1[tid], s1 = b1[H + tid], s2 = b1[2 * H + tid];
    for (int c = 0; c < H; ++c) {
      s0 += b_lift[c] * W1[c * H + tid];
      s1 += b2[c] * W1[H * H + c * H + tid];
      s2 += b2[H + c] * W1[2 * H * H + c * H + tid];
    }
    bia[tid] = s0; bia[H + tid] = s1; bia[2 * H + tid] = s2;
    float su = 0.f;
    for (int c = 0; c < H; ++c) su += W2[2 * H * H + tid * H + c] * W_ro[c];
    u[tid] = su;
  }
  __syncthreads();
  for (int e = tid; e < 512; e += 256) {
    const int t = e >> 8, lane = (e >> 2) & 63, j = e & 3;
    const int lr = lane & 15, q = lane >> 4;
    w0b[e] = (f16)tmp[0][q * 4 + j][t * 16 + lr];
  }
  for (int e = tid; e < 2048; e += 256) {
    const int l = e >> 10, rem = e & 1023;
    const int t = rem >> 9, tp = (rem >> 8) & 1, lane = (rem >> 2) & 63, j = rem & 3;
    const int lr = lane & 15, q = lane >> 4;
    mb[e] = (f16)tmp[1 + l][t * 16 + q * 4 + j][tp * 16 + lr];
  }
  if (tid == 0) {
    float c2r = 0.f;
    for (int k = 0; k < H; ++k) c2r += b2[2 * H + k] * W_ro[k];
    float S = 0.f;
    for (int j = 0; j < N; ++j) S += sred[j];
    cp[0] = c2r * S + b_ro[0];
  }
}

__global__ __launch_bounds__(256, 2)
void gnn_mfma(const float* __restrict__ x,
              const char* __restrict__ ws,
              float* __restrict__ out) {
  const f16* adjb  = (const f16*)(ws + WS_ADJB);
  const f16* w0b   = (const f16*)(ws + WS_W0B);
  const f16* mb    = (const f16*)(ws + WS_MB);
  const float* bia = (const float*)(ws + WS_BIAS);
  const float* v   = (const float*)(ws + WS_V);
  const float* u   = (const float*)(ws + WS_U);
  const float* cp  = (const float*)(ws + WS_C);

  const int tid  = threadIdx.x;
  const int wave = tid >> 6;
  const int lane = tid & 63;
  const int lrow = lane & 15;
  const int quad = lane >> 4;
  const int b    = blockIdx.x * 4 + wave;

  const f32x4 zero = {0.f, 0.f, 0.f, 0.f};

  half4 tf00, tf01, tf10, tf11, tf20, tf21, tf30, tf31,
        tf40, tf41, tf50, tf51, tf60, tf61, tf70, tf71;
  half4 pf00, pf01, pf02, pf03, pf04, pf05, pf06, pf07,
        pf10, pf11, pf12, pf13, pf14, pf15, pf16, pf17;

  // ---- L0: T0[node][fout] = relu(x·W1eff + b0) ----
  {
    const half4 w0 = *(const half4*)(w0b + (0 * 64 + lane) * 4);
    const half4 w1 = *(const half4*)(w0b + (1 * 64 + lane) * 4);
    const float bb0 = bia[lrow], bb1 = bia[16 + lrow];
    const f32x4 bi0 = {bb0, bb0, bb0, bb0};
    const f32x4 bi1 = {bb1, bb1, bb1, bb1};
#define L0G(g, TF0, TF1)                                                     \
    {                                                                        \
      half4 xa = {};                                                         \
      if (quad == 0) {                                                       \
        const float* xr = x + ((size_t)b * N + (g) * 16 + lrow) * 3;         \
        xa = pk4(xr[0], xr[1], xr[2], 0.f);                                  \
      }                                                                      \
      TF0 = relupk(MF(xa, w0, bi0));                                         \
      TF1 = relupk(MF(xa, w1, bi1));                                         \
    }
    L0G(0, tf00, tf01) L0G(1, tf10, tf11) L0G(2, tf20, tf21) L0G(3, tf30, tf31)
    L0G(4, tf40, tf41) L0G(5, tf50, tf51) L0G(6, tf60, tf61) L0G(7, tf70, tf71)
#undef L0G
  }

  // G: P^T[fout t][node gi] = sum_p mfma(A=tf (transpose), B=adj tile pair)
#define GSTEP(gi, P0, P1)                                                    \
  {                                                                          \
    f32x4 a0 = zero, a1 = zero;                                              \
    const f16* ab = adjb + (((gi) * 4) * 64 + lane) * 8;                     \
    half4 h0 = *(const half4*)(ab + 0 * 512 + 0);                            \
    half4 h1 = *(const half4*)(ab + 0 * 512 + 4);                            \
    a0 = MF(tf00, h0, a0); a1 = MF(tf01, h0, a1);                            \
    a0 = MF(tf10, h1, a0); a1 = MF(tf11, h1, a1);                            \
    h0 = *(const half4*)(ab + 1 * 512 + 0);                                  \
    h1 = *(const half4*)(ab + 1 * 512 + 4);                                  \
    a0 = MF(tf20, h0, a0); a1 = MF(tf21, h0, a1);                            \
    a0 = MF(tf30, h1, a0); a1 = MF(tf31, h1, a1);                            \
    h0 = *(const half4*)(ab + 2 * 512 + 0);                                  \
    h1 = *(const half4*)(ab + 2 * 512 + 4);                                  \
    a0 = MF(tf40, h0, a0); a1 = MF(tf41, h0, a1);                            \
    a0 = MF(tf50, h1, a0); a1 = MF(tf51, h1, a1);                            \
    h0 = *(const half4*)(ab + 3 * 512 + 0);                                  \
    h1 = *(const half4*)(ab + 3 * 512 + 4);                                  \
    a0 = MF(tf60, h0, a0); a1 = MF(tf61, h0, a1);                            \
    a0 = MF(tf70, h1, a0); a1 = MF(tf71, h1, a1);                            \
    P0 = pkc(a0); P1 = pkc(a1);                                              \
  }
#define GALL()                                                               \
  GSTEP(0, pf00, pf10) GSTEP(1, pf01, pf11) GSTEP(2, pf02, pf12)             \
  GSTEP(3, pf03, pf13) GSTEP(4, pf04, pf14) GSTEP(5, pf05, pf15)             \
  GSTEP(6, pf06, pf16) GSTEP(7, pf07, pf17)

  GALL()   // G0

  // L1: T1[node][fout'] = relu(P·Meff1 + c1)
  {
    const f16* mbl = mb + 0 * 1024;
    const half4 m00 = *(const half4*)(mbl + ((0 * 2 + 0) * 64 + lane) * 4);
    const half4 m01 = *(const half4*)(mbl + ((0 * 2 + 1) * 64 + lane) * 4);
    const half4 m10 = *(const half4*)(mbl + ((1 * 2 + 0) * 64 + lane) * 4);
    const half4 m11 = *(const half4*)(mbl + ((1 * 2 + 1) * 64 + lane) * 4);
    const float bb0 = bia[H + lrow], bb1 = bia[H + 16 + lrow];
    const f32x4 bi0 = {bb0, bb0, bb0, bb0};
    const f32x4 bi1 = {bb1, bb1, bb1, bb1};
#define L1G(P0, P1, TF0, TF1)                                                \
    {                                                                        \
      f32x4 c0 = MF(P0, m00, bi0); c0 = MF(P1, m10, c0);                     \
      f32x4 c1 = MF(P0, m01, bi1); c1 = MF(P1, m11, c1);                     \
      TF0 = relupk(c0); TF1 = relupk(c1);                                    \
    }
    L1G(pf00, pf10, tf00, tf01) L1G(pf01, pf11, tf10, tf11)
    L1G(pf02, pf12, tf20, tf21) L1G(pf03, pf13, tf30, tf31)
    L1G(pf04, pf14, tf40, tf41) L1G(pf05, pf15, tf50, tf51)
    L1G(pf06, pf16, tf60, tf61) L1G(pf07, pf17, tf70, tf71)
#undef L1G
  }

  GALL()   // G1
#undef GALL
#undef GSTEP

  // ---- L2 + folded readout ----
  {
    const f16* mbl = mb + 1 * 1024;
    const half4 m00 = *(const half4*)(mbl + ((0 * 2 + 0) * 64 + lane) * 4);
    const half4 m01 = *(const half4*)(mbl + ((0 * 2 + 1) * 64 + lane) * 4);
    const half4 m10 = *(const half4*)(mbl + ((1 * 2 + 0) * 64 + lane) * 4);
    const half4 m11 = *(const half4*)(mbl + ((1 * 2 + 1) * 64 + lane) * 4);
    const float bb0 = bia[2 * H + lrow], bb1 = bia[2 * H + 16 + lrow];
    const f32x4 bi0 = {bb0, bb0, bb0, bb0};
    const f32x4 bi1 = {bb1, bb1, bb1, bb1};
    const float u0 = u[lrow], u1 = u[16 + lrow];
    float partial = 0.f;
#define L2G(g, P0, P1)                                                       \
    {                                                                        \
      f32x4 c0 = MF(P0, m00, bi0); c0 = MF(P1, m10, c0);                     \
      f32x4 c1 = MF(P0, m01, bi1); c1 = MF(P1, m11, c1);                     \
      const float4 vv = *(const float4*)(v + (g) * 16 + quad * 4);           \
      partial += (fmaxf(c0[0], 0.f) * vv.x + fmaxf(c0[1], 0.f) * vv.y +      \
                  fmaxf(c0[2], 0.f) * vv.z + fmaxf(c0[3], 0.f) * vv.w) * u0 +\
                 (fmaxf(c1[0], 0.f) * vv.x + fmaxf(c1[1], 0.f) * vv.y +      \
                  fmaxf(c1[2], 0.f) * vv.z + fmaxf(c1[3], 0.f) * vv.w) * u1; \
    }
    L2G(0, pf00, pf10) L2G(1, pf01, pf11) L2G(2, pf02, pf12) L2G(3, pf03, pf13)
    L2G(4, pf04, pf14) L2G(5, pf05, pf15) L2G(6, pf06, pf16) L2G(7, pf07, pf17)
#undef L2G
#pragma unroll
    for (int off = 32; off > 0; off >>= 1) partial += __shfl_down(partial, off, 64);
    if (lane == 0) out[b] = partial + cp[0];
  }
}

extern "C" void kernel_launch(void* const* d_in, const int* in_sizes, int n_in,
                              void* d_out, int out_size, void* d_ws, size_t ws_size,
                              hipStream_t stream) {
  const float* x      = (const float*)d_in[0];
  const float* adj    = (const float*)d_in[1];
  const float* W_lift = (const float*)d_in[2];
  const float* b_lift = (const float*)d_in[3];
  const float* W1     = (const float*)d_in[4];
  const float* b1     = (const float*)d_in[5];
  const float* W2     = (const float*)d_in[6];
  const float* b2     = (const float*)d_in[7];
  const float* W_ro   = (const float*)d_in[8];
  const float* b_ro   = (const float*)d_in[9];
  char* ws = (char*)d_ws;
  float* o = (float*)d_out;

  const int B = in_sizes[0] / (N * 3);   // 16384
  hipLaunchKernelGGL(prep, dim3(1), dim3(256), 0, stream,
                     adj, W_lift, b_lift, W1, b1, W2, b2, W_ro, b_ro, ws);
  hipLaunchKernelGGL(gnn_mfma, dim3(B / 4), dim3(256), 0, stream,
                     x, (const char*)ws, o);
}